// Round 1
// baseline (883.533 us; speedup 1.0000x reference)
//
#include <hip/hip_runtime.h>

// ---------------- CSR build ----------------

__global__ void k_count(const int* __restrict__ ei, int E, int* __restrict__ cnt) {
  int e = blockIdx.x * blockDim.x + threadIdx.x;
  if (e < E) {
    int dst = ei[E + e];
    atomicAdd(&cnt[dst], 1);
  }
}

__global__ void k_scan1(const int* __restrict__ cnt, int* __restrict__ bsum, int n) {
  __shared__ int sh[256];
  int base = blockIdx.x * 1024;
  int t = threadIdx.x;
  int s = 0;
#pragma unroll
  for (int j = 0; j < 4; ++j) {
    int idx = base + t * 4 + j;
    if (idx < n) s += cnt[idx];
  }
  sh[t] = s; __syncthreads();
  for (int off = 128; off > 0; off >>= 1) {
    if (t < off) sh[t] += sh[t + off];
    __syncthreads();
  }
  if (t == 0) bsum[blockIdx.x] = sh[0];
}

__global__ void k_scan2(int* __restrict__ bsum, int B, int* __restrict__ rowptr, int N, int E) {
  __shared__ int sh[256];
  int t = threadIdx.x;
  int v = (t < B) ? bsum[t] : 0;
  sh[t] = v; __syncthreads();
  for (int off = 1; off < 256; off <<= 1) {
    int x = (t >= off) ? sh[t - off] : 0;
    __syncthreads();
    sh[t] += x;
    __syncthreads();
  }
  if (t < B) bsum[t] = sh[t] - v;  // exclusive block offsets
  if (t == 0) rowptr[N] = E;
}

// cnt is consumed and overwritten with the running cursor (= rowptr copy)
__global__ void k_scan3(int* __restrict__ cnt, const int* __restrict__ bsum,
                        int* __restrict__ rowptr, int n) {
  __shared__ int tot[256];
  int base = blockIdx.x * 1024;
  int t = threadIdx.x;
  int v[4]; int s = 0;
#pragma unroll
  for (int j = 0; j < 4; ++j) {
    int idx = base + t * 4 + j;
    v[j] = (idx < n) ? cnt[idx] : 0;
    s += v[j];
  }
  tot[t] = s; __syncthreads();
  for (int off = 1; off < 256; off <<= 1) {
    int x = (t >= off) ? tot[t - off] : 0;
    __syncthreads();
    tot[t] += x;
    __syncthreads();
  }
  int excl = bsum[blockIdx.x] + ((t > 0) ? tot[t - 1] : 0);
#pragma unroll
  for (int j = 0; j < 4; ++j) {
    int idx = base + t * 4 + j;
    if (idx < n) { rowptr[idx] = excl; cnt[idx] = excl; }
    excl += v[j];
  }
}

__global__ void k_fill(const int* __restrict__ ei, int E, int* __restrict__ cursor,
                       int* __restrict__ ssrc) {
  int e = blockIdx.x * blockDim.x + threadIdx.x;
  if (e < E) {
    int src = ei[e];
    int dst = ei[E + e];
    int pos = atomicAdd(&cursor[dst], 1);
    ssrc[pos] = src;
  }
}

// ---------------- mean aggregation (no float atomics) ----------------

__global__ void k_agg(const float* __restrict__ h, const int* __restrict__ rowptr,
                      const int* __restrict__ ssrc, float* __restrict__ agg) {
  int node = blockIdx.x;
  int c = threadIdx.x;  // 0..127
  int beg = rowptr[node], end = rowptr[node + 1];
  float s = 0.f;
  for (int i = beg; i < end; ++i) {
    int src = ssrc[i];  // uniform across block -> scalar load
    s += h[(size_t)src * 128 + c];
  }
  float inv = 1.0f / fmaxf((float)(end - beg), 1.0f);
  agg[(size_t)node * 128 + c] = s * inv;
}

// ---------------- fused dual matmul: out = A@Wl + B@Wr + bias ----------------
// 32 rows per block, 256 threads; each thread: 4 rows x 4 cols patch.

__global__ void __launch_bounds__(256) k_mm(
    const float* __restrict__ A, const float* __restrict__ Bv,
    const float* __restrict__ Wl, const float* __restrict__ Wr,
    const float* __restrict__ bias, float* __restrict__ out, int N) {
  __shared__ float sA[32][128];
  __shared__ float sB[32][128];
  int t = threadIdx.x;
  int r0 = blockIdx.x * 32;
  for (int i = t; i < 32 * 32; i += 256) {  // 32 rows x 32 float4/row
    int r = i >> 5, q = i & 31;
    int gr = r0 + r;
    float4 a = make_float4(0.f, 0.f, 0.f, 0.f), b = a;
    if (gr < N) {
      a = ((const float4*)(A + (size_t)gr * 128))[q];
      b = ((const float4*)(Bv + (size_t)gr * 128))[q];
    }
    ((float4*)sA[r])[q] = a;
    ((float4*)sB[r])[q] = b;
  }
  __syncthreads();

  int cq = (t & 31) * 4;
  int rbase = (t >> 5) * 4;
  float4 acc[4];
#pragma unroll
  for (int j = 0; j < 4; ++j) acc[j] = make_float4(0.f, 0.f, 0.f, 0.f);

#pragma unroll 4
  for (int k = 0; k < 128; ++k) {
    float4 wl = *(const float4*)(Wl + (size_t)k * 128 + cq);
    float4 wr = *(const float4*)(Wr + (size_t)k * 128 + cq);
#pragma unroll
    for (int j = 0; j < 4; ++j) {
      float a = sA[rbase + j][k];
      float b = sB[rbase + j][k];
      acc[j].x += a * wl.x + b * wr.x;
      acc[j].y += a * wl.y + b * wr.y;
      acc[j].z += a * wl.z + b * wr.z;
      acc[j].w += a * wl.w + b * wr.w;
    }
  }

  float4 bi = *(const float4*)(bias + cq);
#pragma unroll
  for (int j = 0; j < 4; ++j) {
    int gr = r0 + rbase + j;
    if (gr < N) {
      float4 o = make_float4(acc[j].x + bi.x, acc[j].y + bi.y,
                             acc[j].z + bi.z, acc[j].w + bi.w);
      *(float4*)(out + (size_t)gr * 128 + cq) = o;
    }
  }
}

// ---------------- graph LayerNorm (scalar stats over all N*C) ----------------

__global__ void k_red(const float* __restrict__ h, size_t total4, double* __restrict__ red) {
  float s = 0.f, s2 = 0.f;
  size_t i0 = (size_t)blockIdx.x * blockDim.x + threadIdx.x;
  size_t stride = (size_t)gridDim.x * blockDim.x;
  for (size_t i = i0; i < total4; i += stride) {
    float4 v = ((const float4*)h)[i];
    s  += v.x + v.y + v.z + v.w;
    s2 += v.x * v.x + v.y * v.y + v.z * v.z + v.w * v.w;
  }
  __shared__ float sh[256], sh2[256];
  int t = threadIdx.x;
  sh[t] = s; sh2[t] = s2; __syncthreads();
  for (int off = 128; off > 0; off >>= 1) {
    if (t < off) { sh[t] += sh[t + off]; sh2[t] += sh2[t + off]; }
    __syncthreads();
  }
  if (t == 0) {
    atomicAdd(&red[0], (double)sh[0]);
    atomicAdd(&red[1], (double)sh2[0]);
  }
}

__global__ void k_fin(const double* __restrict__ red, float* __restrict__ scal, double count) {
  double mu = red[0] / count;
  double var = red[1] / count - mu * mu;
  scal[0] = (float)mu;
  scal[1] = (float)(1.0 / sqrt(var + 1e-5));
}

// normalize + affine + ReLU (+ optional residual), in place
__global__ void k_apply(float* __restrict__ h, const float* __restrict__ xres,
                        const float* __restrict__ scal,
                        const float* __restrict__ gamma, const float* __restrict__ beta,
                        size_t total4) {
  float mu = scal[0], rs = scal[1];
  size_t i0 = (size_t)blockIdx.x * blockDim.x + threadIdx.x;
  size_t stride = (size_t)gridDim.x * blockDim.x;
  for (size_t i = i0; i < total4; i += stride) {
    float4 v = ((const float4*)h)[i];
    int c = (int)((i * 4) & 127);
    float4 g = *(const float4*)(gamma + c);
    float4 b = *(const float4*)(beta + c);
    float4 o;
    o.x = fmaxf((v.x - mu) * rs * g.x + b.x, 0.f);
    o.y = fmaxf((v.y - mu) * rs * g.y + b.y, 0.f);
    o.z = fmaxf((v.z - mu) * rs * g.z + b.z, 0.f);
    o.w = fmaxf((v.w - mu) * rs * g.w + b.w, 0.f);
    if (xres) {
      float4 xr = ((const float4*)xres)[i];
      o.x += xr.x; o.y += xr.y; o.z += xr.z; o.w += xr.w;
    }
    ((float4*)h)[i] = o;
  }
}

// ---------------- launch ----------------

extern "C" void kernel_launch(void* const* d_in, const int* in_sizes, int n_in,
                              void* d_out, int out_size, void* d_ws, size_t ws_size,
                              hipStream_t stream) {
  const float* x   = (const float*)d_in[0];
  const int*   ei  = (const int*)d_in[1];
  const float* Wl1 = (const float*)d_in[2];
  const float* bl1 = (const float*)d_in[3];
  const float* Wr1 = (const float*)d_in[4];
  const float* g1  = (const float*)d_in[5];
  const float* b1  = (const float*)d_in[6];
  const float* Wl2 = (const float*)d_in[7];
  const float* bl2 = (const float*)d_in[8];
  const float* Wr2 = (const float*)d_in[9];
  const float* g2  = (const float*)d_in[10];
  const float* b2  = (const float*)d_in[11];
  float* out = (float*)d_out;

  const int N = in_sizes[0] / 128;
  const int E = in_sizes[1] / 2;

  char* ws = (char*)d_ws;
  size_t off = 0;
  auto alloc = [&](size_t bytes) -> void* {
    void* p = ws + off;
    off = (off + bytes + 255) & ~(size_t)255;
    return p;
  };
  float*  agg    = (float*)alloc((size_t)N * 128 * 4);
  float*  h1     = (float*)alloc((size_t)N * 128 * 4);
  int*    ssrc   = (int*)alloc((size_t)E * 4);
  int*    rowptr = (int*)alloc((size_t)(N + 1) * 4);
  int*    cursor = (int*)alloc((size_t)N * 4);   // counts -> cursors
  int*    bsum   = (int*)alloc(1024);
  double* red    = (double*)alloc(64);
  float*  scal   = (float*)alloc(64);
  (void)ws_size; (void)n_in; (void)out_size;

  const size_t total  = (size_t)N * 128;
  const size_t total4 = total / 4;

  hipMemsetAsync(cursor, 0, (size_t)N * 4, stream);
  hipMemsetAsync(red, 0, 4 * sizeof(double), stream);

  int eb = (E + 255) / 256;
  k_count<<<eb, 256, 0, stream>>>(ei, E, cursor);
  int B = (N + 1023) / 1024;
  k_scan1<<<B, 256, 0, stream>>>(cursor, bsum, N);
  k_scan2<<<1, 256, 0, stream>>>(bsum, B, rowptr, N, E);
  k_scan3<<<B, 256, 0, stream>>>(cursor, bsum, rowptr, N);
  k_fill<<<eb, 256, 0, stream>>>(ei, E, cursor, ssrc);

  // ---- layer 1 ----
  k_agg<<<N, 128, 0, stream>>>(x, rowptr, ssrc, agg);
  k_mm<<<(N + 31) / 32, 256, 0, stream>>>(agg, x, Wl1, Wr1, bl1, h1, N);
  k_red<<<1024, 256, 0, stream>>>(h1, total4, red);
  k_fin<<<1, 1, 0, stream>>>(red, scal, (double)total);
  k_apply<<<2048, 256, 0, stream>>>(h1, (const float*)nullptr, scal, g1, b1, total4);

  // ---- layer 2 ----
  k_agg<<<N, 128, 0, stream>>>(h1, rowptr, ssrc, agg);
  k_mm<<<(N + 31) / 32, 256, 0, stream>>>(agg, h1, Wl2, Wr2, bl2, out, N);
  k_red<<<1024, 256, 0, stream>>>(out, total4, red + 2);
  k_fin<<<1, 1, 0, stream>>>(red + 2, scal + 2, (double)total);
  k_apply<<<2048, 256, 0, stream>>>(out, x, scal + 2, g2, b2, total4);
}

// Round 2
// 720.605 us; speedup vs baseline: 1.2261x; 1.2261x over previous
//
#include <hip/hip_runtime.h>

typedef float  f32x4 __attribute__((ext_vector_type(4)));
typedef short  s16x8 __attribute__((ext_vector_type(8)));

__device__ __forceinline__ float bf2f(unsigned short h) {
  return __uint_as_float(((unsigned int)h) << 16);
}
__device__ __forceinline__ unsigned short f2bf(float f) {
  unsigned int u = __float_as_uint(f);
  unsigned int r = (u + 0x7FFFu + ((u >> 16) & 1u)) >> 16;
  return (unsigned short)r;
}

// ---------------- CSR build ----------------

__global__ void k_count(const int* __restrict__ ei, int E, int* __restrict__ cnt) {
  int e = blockIdx.x * blockDim.x + threadIdx.x;
  if (e < E) atomicAdd(&cnt[ei[E + e]], 1);
}

__global__ void k_scan1(const int* __restrict__ cnt, int* __restrict__ bsum, int n) {
  __shared__ int sh[256];
  int base = blockIdx.x * 1024;
  int t = threadIdx.x;
  int s = 0;
#pragma unroll
  for (int j = 0; j < 4; ++j) {
    int idx = base + t * 4 + j;
    if (idx < n) s += cnt[idx];
  }
  sh[t] = s; __syncthreads();
  for (int off = 128; off > 0; off >>= 1) {
    if (t < off) sh[t] += sh[t + off];
    __syncthreads();
  }
  if (t == 0) bsum[blockIdx.x] = sh[0];
}

__global__ void k_scan2(int* __restrict__ bsum, int B, int* __restrict__ rowptr, int N, int E) {
  __shared__ int sh[256];
  int t = threadIdx.x;
  int v = (t < B) ? bsum[t] : 0;
  sh[t] = v; __syncthreads();
  for (int off = 1; off < 256; off <<= 1) {
    int x = (t >= off) ? sh[t - off] : 0;
    __syncthreads();
    sh[t] += x;
    __syncthreads();
  }
  if (t < B) bsum[t] = sh[t] - v;
  if (t == 0) rowptr[N] = E;
}

__global__ void k_scan3(int* __restrict__ cnt, const int* __restrict__ bsum,
                        int* __restrict__ rowptr, int n) {
  __shared__ int tot[256];
  int base = blockIdx.x * 1024;
  int t = threadIdx.x;
  int v[4]; int s = 0;
#pragma unroll
  for (int j = 0; j < 4; ++j) {
    int idx = base + t * 4 + j;
    v[j] = (idx < n) ? cnt[idx] : 0;
    s += v[j];
  }
  tot[t] = s; __syncthreads();
  for (int off = 1; off < 256; off <<= 1) {
    int x = (t >= off) ? tot[t - off] : 0;
    __syncthreads();
    tot[t] += x;
    __syncthreads();
  }
  int excl = bsum[blockIdx.x] + ((t > 0) ? tot[t - 1] : 0);
#pragma unroll
  for (int j = 0; j < 4; ++j) {
    int idx = base + t * 4 + j;
    if (idx < n) { rowptr[idx] = excl; cnt[idx] = excl; }
    excl += v[j];
  }
}

__global__ void k_fill(const int* __restrict__ ei, int E, int* __restrict__ cursor,
                       int* __restrict__ ssrc) {
  int e = blockIdx.x * blockDim.x + threadIdx.x;
  if (e < E) {
    int pos = atomicAdd(&cursor[ei[E + e]], 1);
    ssrc[pos] = ei[e];
  }
}

// ---------------- fp32 -> bf16 conversion (row-major passthrough) ----------------

__global__ void k_cvt(const float* __restrict__ in, unsigned short* __restrict__ out,
                      size_t total8) {
  size_t i = (size_t)blockIdx.x * blockDim.x + threadIdx.x;
  if (i >= total8) return;
  float4 a = ((const float4*)in)[i * 2];
  float4 b = ((const float4*)in)[i * 2 + 1];
  uint4 o;
  o.x = (unsigned)f2bf(a.x) | ((unsigned)f2bf(a.y) << 16);
  o.y = (unsigned)f2bf(a.z) | ((unsigned)f2bf(a.w) << 16);
  o.z = (unsigned)f2bf(b.x) | ((unsigned)f2bf(b.y) << 16);
  o.w = (unsigned)f2bf(b.z) | ((unsigned)f2bf(b.w) << 16);
  ((uint4*)out)[i] = o;
}

// weights: fp32 row-major W[k][col] (128x128) -> bf16 fragment layout for MFMA B operand.
// WB[((nt*4+kt)*64 + lane)*8 + j] = W[kt*32 + (lane>>4)*8 + j][nt*16 + (lane&15)]
__global__ void k_wcvt(const float* __restrict__ W, unsigned short* __restrict__ WB) {
  int t = blockIdx.x * blockDim.x + threadIdx.x;  // 2048 total
  if (t >= 2048) return;
  int lane = t & 63, kt = (t >> 6) & 3, nt = t >> 8;
  int col = nt * 16 + (lane & 15);
  int k0  = kt * 32 + ((lane >> 4) << 3);
#pragma unroll
  for (int j = 0; j < 8; ++j)
    WB[(((nt * 4 + kt) * 64 + lane) << 3) + j] = f2bf(W[(size_t)(k0 + j) * 128 + col]);
}

// ---------------- mean aggregation: bf16 gather, 4 rows per wave-load ----------------

__global__ void __launch_bounds__(256) k_agg(
    const unsigned short* __restrict__ feat, const int* __restrict__ rowptr,
    const int* __restrict__ ssrc, unsigned short* __restrict__ agg, int N) {
  int wave = threadIdx.x >> 6;
  int lane = threadIdx.x & 63;
  int node = blockIdx.x * 4 + wave;
  if (node >= N) return;
  int g = lane >> 4, sub = lane & 15;
  int beg = rowptr[node], end = rowptr[node + 1];
  float acc[8];
#pragma unroll
  for (int j = 0; j < 8; ++j) acc[j] = 0.f;

  int i = beg + g;
  if (i < end) {
    uint4 q = *(const uint4*)(feat + (size_t)ssrc[i] * 128 + sub * 8);
    for (i += 4; i < end; i += 4) {
      uint4 q2 = *(const uint4*)(feat + (size_t)ssrc[i] * 128 + sub * 8);
#pragma unroll
      for (int w = 0; w < 4; ++w) {
        unsigned int v = ((const unsigned int*)&q)[w];
        acc[2 * w]     += __uint_as_float(v << 16);
        acc[2 * w + 1] += __uint_as_float(v & 0xFFFF0000u);
      }
      q = q2;
    }
#pragma unroll
    for (int w = 0; w < 4; ++w) {
      unsigned int v = ((const unsigned int*)&q)[w];
      acc[2 * w]     += __uint_as_float(v << 16);
      acc[2 * w + 1] += __uint_as_float(v & 0xFFFF0000u);
    }
  }
  // combine the 4 lane-groups (each handled a different subset of neighbors)
#pragma unroll
  for (int j = 0; j < 8; ++j) {
    acc[j] += __shfl_xor(acc[j], 16);
    acc[j] += __shfl_xor(acc[j], 32);
  }
  float inv = 1.0f / fmaxf((float)(end - beg), 1.0f);
  if (g == 0) {
    uint4 o;
#pragma unroll
    for (int w = 0; w < 4; ++w) {
      unsigned int lo = f2bf(acc[2 * w] * inv);
      unsigned int hi = f2bf(acc[2 * w + 1] * inv);
      ((unsigned int*)&o)[w] = lo | (hi << 16);
    }
    *(uint4*)(agg + (size_t)node * 128 + sub * 8) = o;
  }
}

// ---------------- MFMA dual matmul + bias + fused LN partial sums ----------------
// out[r][c] = sum_k A[r][k]*Wl[k][c] + sum_k B[r][k]*Wr[k][c] + bias[c]  (bf16 out)

__global__ void __launch_bounds__(256) k_mm(
    const unsigned short* __restrict__ A, const unsigned short* __restrict__ B,
    const unsigned short* __restrict__ WlB, const unsigned short* __restrict__ WrB,
    const float* __restrict__ bias, unsigned short* __restrict__ out,
    double* __restrict__ red, int N) {
  int t = threadIdx.x;
  int l = t & 63, w = t >> 6;
  int r0 = blockIdx.x * 64 + w * 16;
  int rowA = r0 + (l & 15);
  int rowAc = min(rowA, N - 1);
  const size_t aoff = (size_t)rowAc * 128 + ((l >> 4) << 3);

  f32x4 acc[8];
#pragma unroll
  for (int nt = 0; nt < 8; ++nt) acc[nt] = (f32x4){0.f, 0.f, 0.f, 0.f};

#pragma unroll
  for (int half = 0; half < 2; ++half) {
    const unsigned short* P = half ? B : A;
    const unsigned short* W = half ? WrB : WlB;
#pragma unroll
    for (int kt = 0; kt < 4; ++kt) {
      s16x8 a;
      { uint4 q = *(const uint4*)(P + aoff + kt * 32);
        a = *(const s16x8*)&q; }
#pragma unroll
      for (int nt = 0; nt < 8; ++nt) {
        s16x8 b;
        { uint4 q = *(const uint4*)(W + (((nt * 4 + kt) * 64 + l) << 3));
          b = *(const s16x8*)&q; }
        acc[nt] = __builtin_amdgcn_mfma_f32_16x16x32_bf16(a, b, acc[nt], 0, 0, 0);
      }
    }
  }

  float s = 0.f, s2 = 0.f;
#pragma unroll
  for (int nt = 0; nt < 8; ++nt) {
    float bv = bias[nt * 16 + (l & 15)];
#pragma unroll
    for (int i = 0; i < 4; ++i) {
      int row = r0 + ((l >> 4) << 2) + i;
      float v = acc[nt][i] + bv;
      if (row < N) {
        s += v; s2 += v * v;
        out[(size_t)row * 128 + nt * 16 + (l & 15)] = f2bf(v);
      }
    }
  }
#pragma unroll
  for (int off = 1; off < 64; off <<= 1) {
    s  += __shfl_xor(s, off);
    s2 += __shfl_xor(s2, off);
  }
  if (l == 0) {
    atomicAdd(&red[0], (double)s);
    atomicAdd(&red[1], (double)s2);
  }
}

// ---------------- LN finalize ----------------

__global__ void k_fin(const double* __restrict__ red, float* __restrict__ scal, double count) {
  double mu = red[0] / count;
  double var = red[1] / count - mu * mu;
  scal[0] = (float)mu;
  scal[1] = (float)(1.0 / sqrt(var + 1e-5));
}

// ---------------- normalize + affine + ReLU, bf16 -> bf16 ----------------

__global__ void k_apply1(const unsigned short* __restrict__ h, unsigned short* __restrict__ o,
                         const float* __restrict__ scal,
                         const float* __restrict__ gamma, const float* __restrict__ beta,
                         size_t total8) {
  size_t i = (size_t)blockIdx.x * blockDim.x + threadIdx.x;
  if (i >= total8) return;
  float mu = scal[0], rs = scal[1];
  int c0 = (int)((i * 8) & 127);
  float4 g0 = *(const float4*)(gamma + c0);
  float4 g1 = *(const float4*)(gamma + c0 + 4);
  float4 b0 = *(const float4*)(beta + c0);
  float4 b1 = *(const float4*)(beta + c0 + 4);
  uint4 q = ((const uint4*)h)[i];
  float gg[8] = {g0.x, g0.y, g0.z, g0.w, g1.x, g1.y, g1.z, g1.w};
  float bb[8] = {b0.x, b0.y, b0.z, b0.w, b1.x, b1.y, b1.z, b1.w};
  uint4 ov;
#pragma unroll
  for (int w = 0; w < 4; ++w) {
    unsigned int v = ((const unsigned int*)&q)[w];
    float x0 = __uint_as_float(v << 16);
    float x1 = __uint_as_float(v & 0xFFFF0000u);
    float y0 = fmaxf((x0 - mu) * rs * gg[2 * w] + bb[2 * w], 0.f);
    float y1 = fmaxf((x1 - mu) * rs * gg[2 * w + 1] + bb[2 * w + 1], 0.f);
    ((unsigned int*)&ov)[w] = (unsigned)f2bf(y0) | ((unsigned)f2bf(y1) << 16);
  }
  ((uint4*)o)[i] = ov;
}

// ---------------- normalize + affine + ReLU + residual, bf16 -> fp32 ----------------

__global__ void k_apply2(const unsigned short* __restrict__ h, const float* __restrict__ xres,
                         float* __restrict__ o, const float* __restrict__ scal,
                         const float* __restrict__ gamma, const float* __restrict__ beta,
                         size_t total8) {
  size_t i = (size_t)blockIdx.x * blockDim.x + threadIdx.x;
  if (i >= total8) return;
  float mu = scal[0], rs = scal[1];
  int c0 = (int)((i * 8) & 127);
  float4 g0 = *(const float4*)(gamma + c0);
  float4 g1 = *(const float4*)(gamma + c0 + 4);
  float4 b0 = *(const float4*)(beta + c0);
  float4 b1 = *(const float4*)(beta + c0 + 4);
  uint4 q = ((const uint4*)h)[i];
  float4 xa = ((const float4*)xres)[i * 2];
  float4 xb = ((const float4*)xres)[i * 2 + 1];
  float gg[8] = {g0.x, g0.y, g0.z, g0.w, g1.x, g1.y, g1.z, g1.w};
  float bb[8] = {b0.x, b0.y, b0.z, b0.w, b1.x, b1.y, b1.z, b1.w};
  float xr[8] = {xa.x, xa.y, xa.z, xa.w, xb.x, xb.y, xb.z, xb.w};
  float out8[8];
#pragma unroll
  for (int w = 0; w < 4; ++w) {
    unsigned int v = ((const unsigned int*)&q)[w];
    float x0 = __uint_as_float(v << 16);
    float x1 = __uint_as_float(v & 0xFFFF0000u);
    out8[2 * w]     = fmaxf((x0 - mu) * rs * gg[2 * w] + bb[2 * w], 0.f) + xr[2 * w];
    out8[2 * w + 1] = fmaxf((x1 - mu) * rs * gg[2 * w + 1] + bb[2 * w + 1], 0.f) + xr[2 * w + 1];
  }
  ((float4*)o)[i * 2]     = make_float4(out8[0], out8[1], out8[2], out8[3]);
  ((float4*)o)[i * 2 + 1] = make_float4(out8[4], out8[5], out8[6], out8[7]);
}

// ---------------- launch ----------------

extern "C" void kernel_launch(void* const* d_in, const int* in_sizes, int n_in,
                              void* d_out, int out_size, void* d_ws, size_t ws_size,
                              hipStream_t stream) {
  const float* x   = (const float*)d_in[0];
  const int*   ei  = (const int*)d_in[1];
  const float* Wl1 = (const float*)d_in[2];
  const float* bl1 = (const float*)d_in[3];
  const float* Wr1 = (const float*)d_in[4];
  const float* g1  = (const float*)d_in[5];
  const float* b1  = (const float*)d_in[6];
  const float* Wl2 = (const float*)d_in[7];
  const float* bl2 = (const float*)d_in[8];
  const float* Wr2 = (const float*)d_in[9];
  const float* g2  = (const float*)d_in[10];
  const float* b2  = (const float*)d_in[11];
  float* out = (float*)d_out;

  const int N = in_sizes[0] / 128;
  const int E = in_sizes[1] / 2;

  char* ws = (char*)d_ws;
  size_t off = 0;
  auto alloc = [&](size_t bytes) -> void* {
    void* p = ws + off;
    off = (off + bytes + 255) & ~(size_t)255;
    return p;
  };
  unsigned short* xh   = (unsigned short*)alloc((size_t)N * 128 * 2);
  unsigned short* aggb = (unsigned short*)alloc((size_t)N * 128 * 2);
  unsigned short* hmm  = (unsigned short*)alloc((size_t)N * 128 * 2);
  unsigned short* h1n  = (unsigned short*)alloc((size_t)N * 128 * 2);
  int*    ssrc   = (int*)alloc((size_t)E * 4);
  int*    rowptr = (int*)alloc((size_t)(N + 1) * 4);
  int*    cursor = (int*)alloc((size_t)N * 4);
  int*    bsum   = (int*)alloc(1024);
  double* red    = (double*)alloc(64);
  float*  scal   = (float*)alloc(64);
  unsigned short* Wl1b = (unsigned short*)alloc(128 * 128 * 2);
  unsigned short* Wr1b = (unsigned short*)alloc(128 * 128 * 2);
  unsigned short* Wl2b = (unsigned short*)alloc(128 * 128 * 2);
  unsigned short* Wr2b = (unsigned short*)alloc(128 * 128 * 2);
  (void)ws_size; (void)n_in; (void)out_size;

  const size_t total  = (size_t)N * 128;
  const size_t total8 = total / 8;
  const int applyGrid = (int)((total8 + 255) / 256);

  hipMemsetAsync(cursor, 0, (size_t)N * 4, stream);
  hipMemsetAsync(red, 0, 4 * sizeof(double), stream);

  int eb = (E + 255) / 256;
  k_count<<<eb, 256, 0, stream>>>(ei, E, cursor);
  int B = (N + 1023) / 1024;
  k_scan1<<<B, 256, 0, stream>>>(cursor, bsum, N);
  k_scan2<<<1, 256, 0, stream>>>(bsum, B, rowptr, N, E);
  k_scan3<<<B, 256, 0, stream>>>(cursor, bsum, rowptr, N);
  k_fill<<<eb, 256, 0, stream>>>(ei, E, cursor, ssrc);

  k_cvt<<<applyGrid, 256, 0, stream>>>(x, xh, total8);
  k_wcvt<<<8, 256, 0, stream>>>(Wl1, Wl1b);
  k_wcvt<<<8, 256, 0, stream>>>(Wr1, Wr1b);
  k_wcvt<<<8, 256, 0, stream>>>(Wl2, Wl2b);
  k_wcvt<<<8, 256, 0, stream>>>(Wr2, Wr2b);

  const int mmGrid = (N + 63) / 64;

  // ---- layer 1 ----
  k_agg<<<(N + 3) / 4, 256, 0, stream>>>(xh, rowptr, ssrc, aggb, N);
  k_mm<<<mmGrid, 256, 0, stream>>>(aggb, xh, Wl1b, Wr1b, bl1, hmm, red, N);
  k_fin<<<1, 1, 0, stream>>>(red, scal, (double)total);
  k_apply1<<<applyGrid, 256, 0, stream>>>(hmm, h1n, scal, g1, b1, total8);

  // ---- layer 2 ----
  k_agg<<<(N + 3) / 4, 256, 0, stream>>>(h1n, rowptr, ssrc, aggb, N);
  k_mm<<<mmGrid, 256, 0, stream>>>(aggb, h1n, Wl2b, Wr2b, bl2, hmm, red + 2, N);
  k_fin<<<1, 1, 0, stream>>>(red + 2, scal + 2, (double)total);
  k_apply2<<<applyGrid, 256, 0, stream>>>(hmm, x, out, scal + 2, g2, b2, total8);
}

// Round 3
// 467.219 us; speedup vs baseline: 1.8910x; 1.5423x over previous
//
#include <hip/hip_runtime.h>

typedef float  f32x4 __attribute__((ext_vector_type(4)));
typedef short  s16x8 __attribute__((ext_vector_type(8)));

__device__ __forceinline__ float bf2f(unsigned short h) {
  return __uint_as_float(((unsigned int)h) << 16);
}
__device__ __forceinline__ unsigned short f2bf(float f) {
  unsigned int u = __float_as_uint(f);
  unsigned int r = (u + 0x7FFFu + ((u >> 16) & 1u)) >> 16;
  return (unsigned short)r;
}

// ---------------- CSR build ----------------

__global__ void k_count(const int* __restrict__ ei, int E, int* __restrict__ cnt) {
  int e = blockIdx.x * blockDim.x + threadIdx.x;
  if (e < E) atomicAdd(&cnt[ei[E + e]], 1);
}

__global__ void k_scan1(const int* __restrict__ cnt, int* __restrict__ bsum, int n) {
  __shared__ int sh[256];
  int base = blockIdx.x * 1024;
  int t = threadIdx.x;
  int s = 0;
#pragma unroll
  for (int j = 0; j < 4; ++j) {
    int idx = base + t * 4 + j;
    if (idx < n) s += cnt[idx];
  }
  sh[t] = s; __syncthreads();
  for (int off = 128; off > 0; off >>= 1) {
    if (t < off) sh[t] += sh[t + off];
    __syncthreads();
  }
  if (t == 0) bsum[blockIdx.x] = sh[0];
}

__global__ void k_scan2(int* __restrict__ bsum, int B, int* __restrict__ rowptr, int N, int E) {
  __shared__ int sh[256];
  int t = threadIdx.x;
  int v = (t < B) ? bsum[t] : 0;
  sh[t] = v; __syncthreads();
  for (int off = 1; off < 256; off <<= 1) {
    int x = (t >= off) ? sh[t - off] : 0;
    __syncthreads();
    sh[t] += x;
    __syncthreads();
  }
  if (t < B) bsum[t] = sh[t] - v;
  if (t == 0) rowptr[N] = E;
}

__global__ void k_scan3(int* __restrict__ cnt, const int* __restrict__ bsum,
                        int* __restrict__ rowptr, int n) {
  __shared__ int tot[256];
  int base = blockIdx.x * 1024;
  int t = threadIdx.x;
  int v[4]; int s = 0;
#pragma unroll
  for (int j = 0; j < 4; ++j) {
    int idx = base + t * 4 + j;
    v[j] = (idx < n) ? cnt[idx] : 0;
    s += v[j];
  }
  tot[t] = s; __syncthreads();
  for (int off = 1; off < 256; off <<= 1) {
    int x = (t >= off) ? tot[t - off] : 0;
    __syncthreads();
    tot[t] += x;
    __syncthreads();
  }
  int excl = bsum[blockIdx.x] + ((t > 0) ? tot[t - 1] : 0);
#pragma unroll
  for (int j = 0; j < 4; ++j) {
    int idx = base + t * 4 + j;
    if (idx < n) { rowptr[idx] = excl; cnt[idx] = excl; }
    excl += v[j];
  }
}

__global__ void k_fill(const int* __restrict__ ei, int E, int* __restrict__ cursor,
                       int* __restrict__ ssrc) {
  int e = blockIdx.x * blockDim.x + threadIdx.x;
  if (e < E) {
    int pos = atomicAdd(&cursor[ei[E + e]], 1);
    ssrc[pos] = ei[e];
  }
}

// ---------------- fp32 -> bf16 conversion ----------------

__global__ void k_cvt(const float* __restrict__ in, unsigned short* __restrict__ out,
                      size_t total8) {
  size_t i = (size_t)blockIdx.x * blockDim.x + threadIdx.x;
  if (i >= total8) return;
  float4 a = ((const float4*)in)[i * 2];
  float4 b = ((const float4*)in)[i * 2 + 1];
  uint4 o;
  o.x = (unsigned)f2bf(a.x) | ((unsigned)f2bf(a.y) << 16);
  o.y = (unsigned)f2bf(a.z) | ((unsigned)f2bf(a.w) << 16);
  o.z = (unsigned)f2bf(b.x) | ((unsigned)f2bf(b.y) << 16);
  o.w = (unsigned)f2bf(b.z) | ((unsigned)f2bf(b.w) << 16);
  ((uint4*)out)[i] = o;
}

// weights: fp32 row-major W[k][col] (128x128) -> bf16 MFMA B-fragment layout
__global__ void k_wcvt(const float* __restrict__ W, unsigned short* __restrict__ WB) {
  int t = blockIdx.x * blockDim.x + threadIdx.x;  // 2048 total
  if (t >= 2048) return;
  int lane = t & 63, kt = (t >> 6) & 3, nt = t >> 8;
  int col = nt * 16 + (lane & 15);
  int k0  = kt * 32 + ((lane >> 4) << 3);
#pragma unroll
  for (int j = 0; j < 8; ++j)
    WB[(((nt * 4 + kt) * 64 + lane) << 3) + j] = f2bf(W[(size_t)(k0 + j) * 128 + col]);
}

// ---------------- mean aggregation: bf16 gather, 4 rows per wave-load ----------------

__global__ void __launch_bounds__(256) k_agg(
    const unsigned short* __restrict__ feat, const int* __restrict__ rowptr,
    const int* __restrict__ ssrc, unsigned short* __restrict__ agg, int N) {
  int wave = threadIdx.x >> 6;
  int lane = threadIdx.x & 63;
  int node = blockIdx.x * 4 + wave;
  if (node >= N) return;
  int g = lane >> 4, sub = lane & 15;
  int beg = rowptr[node], end = rowptr[node + 1];
  float acc[8];
#pragma unroll
  for (int j = 0; j < 8; ++j) acc[j] = 0.f;

  int i = beg + g;
  if (i < end) {
    uint4 q = *(const uint4*)(feat + (size_t)ssrc[i] * 128 + sub * 8);
    for (i += 4; i < end; i += 4) {
      uint4 q2 = *(const uint4*)(feat + (size_t)ssrc[i] * 128 + sub * 8);
#pragma unroll
      for (int w = 0; w < 4; ++w) {
        unsigned int v = ((const unsigned int*)&q)[w];
        acc[2 * w]     += __uint_as_float(v << 16);
        acc[2 * w + 1] += __uint_as_float(v & 0xFFFF0000u);
      }
      q = q2;
    }
#pragma unroll
    for (int w = 0; w < 4; ++w) {
      unsigned int v = ((const unsigned int*)&q)[w];
      acc[2 * w]     += __uint_as_float(v << 16);
      acc[2 * w + 1] += __uint_as_float(v & 0xFFFF0000u);
    }
  }
#pragma unroll
  for (int j = 0; j < 8; ++j) {
    acc[j] += __shfl_xor(acc[j], 16);
    acc[j] += __shfl_xor(acc[j], 32);
  }
  float inv = 1.0f / fmaxf((float)(end - beg), 1.0f);
  if (g == 0) {
    uint4 o;
#pragma unroll
    for (int w = 0; w < 4; ++w) {
      unsigned int lo = f2bf(acc[2 * w] * inv);
      unsigned int hi = f2bf(acc[2 * w + 1] * inv);
      ((unsigned int*)&o)[w] = lo | (hi << 16);
    }
    *(uint4*)(agg + (size_t)node * 128 + sub * 8) = o;
  }
}

// ---------------- MFMA dual matmul + bias + fused LN partials ----------------
// out[r][c] = A[r]@Wl[:,c] + B[r]@Wr[:,c] + bias[c]  (bf16 out)
// Epilogue via padded LDS -> coalesced 16B stores; LN sums -> 256 f64 buckets.

__global__ void __launch_bounds__(256) k_mm(
    const unsigned short* __restrict__ A, const unsigned short* __restrict__ B,
    const unsigned short* __restrict__ WlB, const unsigned short* __restrict__ WrB,
    const float* __restrict__ bias, unsigned short* __restrict__ out,
    double* __restrict__ red, int N) {
  __shared__ __align__(16) float lsd[4][16][132];
  int t = threadIdx.x;
  int l = t & 63, w = t >> 6;
  int r0 = blockIdx.x * 64 + w * 16;
  int c = l & 15;
  int rb = (l >> 4) << 2;
  int rowA = r0 + c;
  int rowAc = min(rowA, N - 1);
  const size_t aoff = (size_t)rowAc * 128 + ((l >> 4) << 3);

  f32x4 acc[8];
#pragma unroll
  for (int nt = 0; nt < 8; ++nt) acc[nt] = (f32x4){0.f, 0.f, 0.f, 0.f};

#pragma unroll
  for (int half = 0; half < 2; ++half) {
    const unsigned short* P = half ? B : A;
    const unsigned short* W = half ? WrB : WlB;
#pragma unroll
    for (int kt = 0; kt < 4; ++kt) {
      s16x8 a;
      { uint4 q = *(const uint4*)(P + aoff + kt * 32);
        a = *(const s16x8*)&q; }
#pragma unroll
      for (int nt = 0; nt < 8; ++nt) {
        s16x8 b;
        { uint4 q = *(const uint4*)(W + (((nt * 4 + kt) * 64 + l) << 3));
          b = *(const s16x8*)&q; }
        acc[nt] = __builtin_amdgcn_mfma_f32_16x16x32_bf16(a, b, acc[nt], 0, 0, 0);
      }
    }
  }

  // bias + LN partials; stage into LDS for vectorized stores
  float s = 0.f, s2 = 0.f;
#pragma unroll
  for (int nt = 0; nt < 8; ++nt) {
    float bv = bias[nt * 16 + c];
#pragma unroll
    for (int i = 0; i < 4; ++i) {
      float v = acc[nt][i] + bv;
      if (r0 + rb + i < N) { s += v; s2 += v * v; }
      lsd[w][rb + i][nt * 16 + c] = v;
    }
  }
  __syncthreads();

  // coalesced bf16 stores: per wave 16 rows x 16 chunks of 16B
#pragma unroll
  for (int j = 0; j < 4; ++j) {
    int idx = j * 64 + l;            // 0..255
    int riw = idx >> 4;              // row in wave
    int chunk = idx & 15;            // 16B chunk in row
    int row = r0 + riw;
    if (row < N) {
      float4 v0 = *(const float4*)&lsd[w][riw][chunk * 8];
      float4 v1 = *(const float4*)&lsd[w][riw][chunk * 8 + 4];
      uint4 o;
      o.x = (unsigned)f2bf(v0.x) | ((unsigned)f2bf(v0.y) << 16);
      o.y = (unsigned)f2bf(v0.z) | ((unsigned)f2bf(v0.w) << 16);
      o.z = (unsigned)f2bf(v1.x) | ((unsigned)f2bf(v1.y) << 16);
      o.w = (unsigned)f2bf(v1.z) | ((unsigned)f2bf(v1.w) << 16);
      *(uint4*)(out + (size_t)row * 128 + chunk * 8) = o;
    }
  }

  // LN partial reduce within wave, then bucketed f64 atomics (no hot-spot)
#pragma unroll
  for (int off = 1; off < 64; off <<= 1) {
    s  += __shfl_xor(s, off);
    s2 += __shfl_xor(s2, off);
  }
  if (l == 0) {
    int bucket = (blockIdx.x * 4 + w) & 255;
    atomicAdd(&red[2 * bucket],     (double)s);
    atomicAdd(&red[2 * bucket + 1], (double)s2);
  }
}

// ---------------- LN finalize: reduce 256 buckets ----------------

__global__ void k_fin(const double* __restrict__ red, float* __restrict__ scal, double count) {
  __shared__ double sh[256], sh2[256];
  int t = threadIdx.x;
  sh[t] = red[2 * t]; sh2[t] = red[2 * t + 1];
  __syncthreads();
  for (int off = 128; off > 0; off >>= 1) {
    if (t < off) { sh[t] += sh[t + off]; sh2[t] += sh2[t + off]; }
    __syncthreads();
  }
  if (t == 0) {
    double mu = sh[0] / count;
    double var = sh2[0] / count - mu * mu;
    scal[0] = (float)mu;
    scal[1] = (float)(1.0 / sqrt(var + 1e-5));
  }
}

// ---------------- normalize + affine + ReLU, bf16 -> bf16 ----------------

__global__ void k_apply1(const unsigned short* __restrict__ h, unsigned short* __restrict__ o,
                         const float* __restrict__ scal,
                         const float* __restrict__ gamma, const float* __restrict__ beta,
                         size_t total8) {
  size_t i = (size_t)blockIdx.x * blockDim.x + threadIdx.x;
  if (i >= total8) return;
  float mu = scal[0], rs = scal[1];
  int c0 = (int)((i * 8) & 127);
  float4 g0 = *(const float4*)(gamma + c0);
  float4 g1 = *(const float4*)(gamma + c0 + 4);
  float4 b0 = *(const float4*)(beta + c0);
  float4 b1 = *(const float4*)(beta + c0 + 4);
  uint4 q = ((const uint4*)h)[i];
  float gg[8] = {g0.x, g0.y, g0.z, g0.w, g1.x, g1.y, g1.z, g1.w};
  float bb[8] = {b0.x, b0.y, b0.z, b0.w, b1.x, b1.y, b1.z, b1.w};
  uint4 ov;
#pragma unroll
  for (int w = 0; w < 4; ++w) {
    unsigned int v = ((const unsigned int*)&q)[w];
    float x0 = __uint_as_float(v << 16);
    float x1 = __uint_as_float(v & 0xFFFF0000u);
    float y0 = fmaxf((x0 - mu) * rs * gg[2 * w] + bb[2 * w], 0.f);
    float y1 = fmaxf((x1 - mu) * rs * gg[2 * w + 1] + bb[2 * w + 1], 0.f);
    ((unsigned int*)&ov)[w] = (unsigned)f2bf(y0) | ((unsigned)f2bf(y1) << 16);
  }
  ((uint4*)o)[i] = ov;
}

// ---------------- normalize + affine + ReLU + residual, bf16 -> fp32 ----------------

__global__ void k_apply2(const unsigned short* __restrict__ h, const float* __restrict__ xres,
                         float* __restrict__ o, const float* __restrict__ scal,
                         const float* __restrict__ gamma, const float* __restrict__ beta,
                         size_t total8) {
  size_t i = (size_t)blockIdx.x * blockDim.x + threadIdx.x;
  if (i >= total8) return;
  float mu = scal[0], rs = scal[1];
  int c0 = (int)((i * 8) & 127);
  float4 g0 = *(const float4*)(gamma + c0);
  float4 g1 = *(const float4*)(gamma + c0 + 4);
  float4 b0 = *(const float4*)(beta + c0);
  float4 b1 = *(const float4*)(beta + c0 + 4);
  uint4 q = ((const uint4*)h)[i];
  float4 xa = ((const float4*)xres)[i * 2];
  float4 xb = ((const float4*)xres)[i * 2 + 1];
  float gg[8] = {g0.x, g0.y, g0.z, g0.w, g1.x, g1.y, g1.z, g1.w};
  float bb[8] = {b0.x, b0.y, b0.z, b0.w, b1.x, b1.y, b1.z, b1.w};
  float xr[8] = {xa.x, xa.y, xa.z, xa.w, xb.x, xb.y, xb.z, xb.w};
  float out8[8];
#pragma unroll
  for (int w = 0; w < 4; ++w) {
    unsigned int v = ((const unsigned int*)&q)[w];
    float x0 = __uint_as_float(v << 16);
    float x1 = __uint_as_float(v & 0xFFFF0000u);
    out8[2 * w]     = fmaxf((x0 - mu) * rs * gg[2 * w] + bb[2 * w], 0.f) + xr[2 * w];
    out8[2 * w + 1] = fmaxf((x1 - mu) * rs * gg[2 * w + 1] + bb[2 * w + 1], 0.f) + xr[2 * w + 1];
  }
  ((float4*)o)[i * 2]     = make_float4(out8[0], out8[1], out8[2], out8[3]);
  ((float4*)o)[i * 2 + 1] = make_float4(out8[4], out8[5], out8[6], out8[7]);
}

// ---------------- launch ----------------

extern "C" void kernel_launch(void* const* d_in, const int* in_sizes, int n_in,
                              void* d_out, int out_size, void* d_ws, size_t ws_size,
                              hipStream_t stream) {
  const float* x   = (const float*)d_in[0];
  const int*   ei  = (const int*)d_in[1];
  const float* Wl1 = (const float*)d_in[2];
  const float* bl1 = (const float*)d_in[3];
  const float* Wr1 = (const float*)d_in[4];
  const float* g1  = (const float*)d_in[5];
  const float* b1  = (const float*)d_in[6];
  const float* Wl2 = (const float*)d_in[7];
  const float* bl2 = (const float*)d_in[8];
  const float* Wr2 = (const float*)d_in[9];
  const float* g2  = (const float*)d_in[10];
  const float* b2  = (const float*)d_in[11];
  float* out = (float*)d_out;

  const int N = in_sizes[0] / 128;
  const int E = in_sizes[1] / 2;

  char* ws = (char*)d_ws;
  size_t off = 0;
  auto alloc = [&](size_t bytes) -> void* {
    void* p = ws + off;
    off = (off + bytes + 255) & ~(size_t)255;
    return p;
  };
  unsigned short* xh   = (unsigned short*)alloc((size_t)N * 128 * 2);
  unsigned short* aggb = (unsigned short*)alloc((size_t)N * 128 * 2);
  unsigned short* hmm  = (unsigned short*)alloc((size_t)N * 128 * 2);
  unsigned short* h1n  = (unsigned short*)alloc((size_t)N * 128 * 2);
  int*    ssrc   = (int*)alloc((size_t)E * 4);
  int*    rowptr = (int*)alloc((size_t)(N + 1) * 4);
  int*    cursor = (int*)alloc((size_t)N * 4);
  int*    bsum   = (int*)alloc(1024);
  double* red    = (double*)alloc(2 * 512 * sizeof(double));  // 2 layers x 256 buckets x 2
  float*  scal   = (float*)alloc(64);
  unsigned short* Wl1b = (unsigned short*)alloc(128 * 128 * 2);
  unsigned short* Wr1b = (unsigned short*)alloc(128 * 128 * 2);
  unsigned short* Wl2b = (unsigned short*)alloc(128 * 128 * 2);
  unsigned short* Wr2b = (unsigned short*)alloc(128 * 128 * 2);
  (void)ws_size; (void)n_in; (void)out_size;

  const size_t total  = (size_t)N * 128;
  const size_t total8 = total / 8;
  const int applyGrid = (int)((total8 + 255) / 256);

  hipMemsetAsync(cursor, 0, (size_t)N * 4, stream);
  hipMemsetAsync(red, 0, 2 * 512 * sizeof(double), stream);

  int eb = (E + 255) / 256;
  k_count<<<eb, 256, 0, stream>>>(ei, E, cursor);
  int B = (N + 1023) / 1024;
  k_scan1<<<B, 256, 0, stream>>>(cursor, bsum, N);
  k_scan2<<<1, 256, 0, stream>>>(bsum, B, rowptr, N, E);
  k_scan3<<<B, 256, 0, stream>>>(cursor, bsum, rowptr, N);
  k_fill<<<eb, 256, 0, stream>>>(ei, E, cursor, ssrc);

  k_cvt<<<applyGrid, 256, 0, stream>>>(x, xh, total8);
  k_wcvt<<<8, 256, 0, stream>>>(Wl1, Wl1b);
  k_wcvt<<<8, 256, 0, stream>>>(Wr1, Wr1b);
  k_wcvt<<<8, 256, 0, stream>>>(Wl2, Wl2b);
  k_wcvt<<<8, 256, 0, stream>>>(Wr2, Wr2b);

  const int mmGrid = (N + 63) / 64;

  // ---- layer 1 ----
  k_agg<<<(N + 3) / 4, 256, 0, stream>>>(xh, rowptr, ssrc, aggb, N);
  k_mm<<<mmGrid, 256, 0, stream>>>(aggb, xh, Wl1b, Wr1b, bl1, hmm, red, N);
  k_fin<<<1, 256, 0, stream>>>(red, scal, (double)total);
  k_apply1<<<applyGrid, 256, 0, stream>>>(hmm, h1n, scal, g1, b1, total8);

  // ---- layer 2 ----
  k_agg<<<(N + 3) / 4, 256, 0, stream>>>(h1n, rowptr, ssrc, aggb, N);
  k_mm<<<mmGrid, 256, 0, stream>>>(aggb, h1n, Wl2b, Wr2b, bl2, hmm, red + 512, N);
  k_fin<<<1, 256, 0, stream>>>(red + 512, scal + 2, (double)total);
  k_apply2<<<applyGrid, 256, 0, stream>>>(hmm, x, out, scal + 2, g2, b2, total8);
}